// Round 12
// baseline (584.346 us; speedup 1.0000x reference)
//
#include <hip/hip_runtime.h>
#include <math.h>

#define SEQ 4096
#define DM  1024
#define NH  16
#define DK  64

typedef __attribute__((ext_vector_type(4))) float f32x4;
typedef __attribute__((ext_vector_type(8))) short bf16x8;
typedef __attribute__((ext_vector_type(8))) unsigned short u16x8;

union FragU { u16x8 u; bf16x8 b; ushort4 q[2]; unsigned w[4]; };

__device__ __forceinline__ unsigned cvtpk(float a, float b) {
    unsigned r; asm("v_cvt_pk_bf16_f32 %0, %1, %2" : "=v"(r) : "v"(a), "v"(b)); return r;
}
__device__ __forceinline__ float fexp2(float x) {
    float r; asm("v_exp_f32 %0, %1" : "=v"(r) : "v"(x)); return r;
}
__device__ __forceinline__ float bf_f(unsigned short s) {
    return __uint_as_float(((unsigned)s) << 16);
}
__device__ __forceinline__ void split4(float4 v, ushort4& hv, ushort4& lv) {
    union { ushort4 q; unsigned w[2]; } H, L;
    H.w[0] = cvtpk(v.x, v.y); H.w[1] = cvtpk(v.z, v.w);
    const float rx = v.x - __uint_as_float(H.w[0] << 16);
    const float ry = v.y - __uint_as_float(H.w[0] & 0xffff0000u);
    const float rz = v.z - __uint_as_float(H.w[1] << 16);
    const float rw = v.w - __uint_as_float(H.w[1] & 0xffff0000u);
    L.w[0] = cvtpk(rx, ry); L.w[1] = cvtpk(rz, rw);
    hv = H.q; lv = L.q;
}
__device__ __forceinline__ void split1(float f, unsigned short& h, unsigned short& l) {
    const unsigned hw = cvtpk(f, f) & 0xffffu;
    h = (unsigned short)hw;
    const float r = f - __uint_as_float(hw << 16);
    l = (unsigned short)(__float_as_uint(r) >> 16);
}

// ---------------------------------------------------------------------------
// Pre-split fp32 -> bf16 hi/lo (RNE).
// ---------------------------------------------------------------------------
__global__ __launch_bounds__(256)
void split_f32(const float* __restrict__ src, unsigned short* __restrict__ hi,
               unsigned short* __restrict__ lo, int n4)
{
    const int stride = gridDim.x * 256;
    for (int i = blockIdx.x * 256 + threadIdx.x; i < n4; i += stride) {
        const float4 v = reinterpret_cast<const float4*>(src)[i];
        ushort4 hv, lv;
        split4(v, hv, lv);
        reinterpret_cast<ushort4*>(hi)[i] = hv;
        reinterpret_cast<ushort4*>(lo)[i] = lv;
    }
}

// ---------------------------------------------------------------------------
// MFMA GEMM, 3-term bf16 hi/lo emulation. C = A * W^T.  (unchanged, validated)
// A pre-split bf16 hi/lo. W fp32, split in-loop.
// MODE 4: fused QKV (Q/K RoPE+store, V hi-only transposed). MODE 0: Wo->fp32.
// ---------------------------------------------------------------------------
template<int MODE>
__global__ __launch_bounds__(256, 2)
void gemm_mfma(const unsigned short* __restrict__ Ahi, const unsigned short* __restrict__ Alo,
               const float* __restrict__ W0, const float* __restrict__ W1,
               const float* __restrict__ W2,
               unsigned short* __restrict__ OQh, unsigned short* __restrict__ OQl,
               unsigned short* __restrict__ OKh, unsigned short* __restrict__ OKl,
               unsigned short* __restrict__ OVh,
               float* __restrict__ Ofp,
               const float* __restrict__ cosT, const float* __restrict__ sinT,
               const int* __restrict__ positions)
{
    constexpr int NT = (MODE == 4) ? 24 : 8;   // n-tiles of 128
    __shared__ unsigned short As[128][76];
    __shared__ unsigned short Bs[128][76];

    const int t   = threadIdx.x;
    const int bid = blockIdx.x;
    const int qpx = (32 * NT) >> 3;
    const int swz = (bid & 7) * qpx + (bid >> 3);
    const int by  = swz / NT;
    const int bxf = swz % NT;
    const int wt  = (MODE == 4) ? (bxf >> 3) : 0;
    const int bx  = (MODE == 4) ? (bxf & 7) : bxf;
    const int m0  = by * 128;
    const float* W = (MODE == 4) ? (wt == 0 ? W0 : (wt == 1 ? W1 : W2)) : W0;

    const int lane = t & 63, w = t >> 6;
    const int wr = w >> 1, wc = w & 1;
    const int l15 = lane & 15, lg = lane >> 4;

    const int ar = t >> 1, ah = t & 1;
    const unsigned short* Aph = &Ahi[(size_t)(m0 + ar) * DM + ah * 16];
    const unsigned short* Apl = &Alo[(size_t)(m0 + ar) * DM + ah * 16];
    const float* Wp = &W[(size_t)(bx * 128 + ar) * DM + ah * 16];

    f32x4 acc[4][4];
#pragma unroll
    for (int mi = 0; mi < 4; ++mi)
#pragma unroll
        for (int ni = 0; ni < 4; ++ni) acc[mi][ni] = (f32x4){0.f, 0.f, 0.f, 0.f};

    float4 pb[4];
    u16x8 pah[2], pal[2];
    pah[0] = *reinterpret_cast<const u16x8*>(Aph);
    pah[1] = *reinterpret_cast<const u16x8*>(Aph + 8);
    pal[0] = *reinterpret_cast<const u16x8*>(Apl);
    pal[1] = *reinterpret_cast<const u16x8*>(Apl + 8);
#pragma unroll
    for (int g = 0; g < 4; ++g) pb[g] = *reinterpret_cast<const float4*>(Wp + g * 4);

    for (int kt = 0; kt < 32; ++kt) {
        {
            FragU h0, h1, l0, l1;
            h0.u = pah[0]; h1.u = pah[1]; l0.u = pal[0]; l1.u = pal[1];
            *reinterpret_cast<ushort4*>(&As[ar][0  + 4 * ah]) = h0.q[0];
            *reinterpret_cast<ushort4*>(&As[ar][8  + 4 * ah]) = h0.q[1];
            *reinterpret_cast<ushort4*>(&As[ar][16 + 4 * ah]) = h1.q[0];
            *reinterpret_cast<ushort4*>(&As[ar][24 + 4 * ah]) = h1.q[1];
            *reinterpret_cast<ushort4*>(&As[ar][32 + 4 * ah]) = l0.q[0];
            *reinterpret_cast<ushort4*>(&As[ar][40 + 4 * ah]) = l0.q[1];
            *reinterpret_cast<ushort4*>(&As[ar][48 + 4 * ah]) = l1.q[0];
            *reinterpret_cast<ushort4*>(&As[ar][56 + 4 * ah]) = l1.q[1];
        }
#pragma unroll
        for (int g = 0; g < 4; ++g) {
            ushort4 hv, lv;
            split4(pb[g], hv, lv);
            *reinterpret_cast<ushort4*>(&Bs[ar][8 * g + 4 * ah])      = hv;
            *reinterpret_cast<ushort4*>(&Bs[ar][32 + 8 * g + 4 * ah]) = lv;
        }
        __syncthreads();

        if (kt < 31) {
            const int ko = (kt + 1) * 32;
            pah[0] = *reinterpret_cast<const u16x8*>(Aph + ko);
            pah[1] = *reinterpret_cast<const u16x8*>(Aph + ko + 8);
            pal[0] = *reinterpret_cast<const u16x8*>(Apl + ko);
            pal[1] = *reinterpret_cast<const u16x8*>(Apl + ko + 8);
#pragma unroll
            for (int g = 0; g < 4; ++g)
                pb[g] = *reinterpret_cast<const float4*>(Wp + ko + g * 4);
        }

        FragU b_h[4], b_l[4];
#pragma unroll
        for (int ni = 0; ni < 4; ++ni) {
            const int row = wc * 64 + ni * 16 + l15;
            b_h[ni].u = *reinterpret_cast<const u16x8*>(&Bs[row][8 * lg]);
            b_l[ni].u = *reinterpret_cast<const u16x8*>(&Bs[row][32 + 8 * lg]);
        }
#pragma unroll
        for (int mi = 0; mi < 4; ++mi) {
            FragU a_h, a_l;
            const int row = wr * 64 + mi * 16 + l15;
            a_h.u = *reinterpret_cast<const u16x8*>(&As[row][8 * lg]);
            a_l.u = *reinterpret_cast<const u16x8*>(&As[row][32 + 8 * lg]);
#pragma unroll
            for (int ni = 0; ni < 4; ++ni) {
                f32x4 c = acc[mi][ni];
                c = __builtin_amdgcn_mfma_f32_16x16x32_bf16(a_h.b, b_h[ni].b, c, 0, 0, 0);
                c = __builtin_amdgcn_mfma_f32_16x16x32_bf16(a_h.b, b_l[ni].b, c, 0, 0, 0);
                c = __builtin_amdgcn_mfma_f32_16x16x32_bf16(a_l.b, b_h[ni].b, c, 0, 0, 0);
                acc[mi][ni] = c;
            }
        }
        __syncthreads();
    }

    if constexpr (MODE == 0) {
#pragma unroll
        for (int mi = 0; mi < 4; ++mi)
#pragma unroll
            for (int ni = 0; ni < 4; ++ni)
#pragma unroll
                for (int r = 0; r < 4; ++r) {
                    const int m = m0 + wr * 64 + mi * 16 + lg * 4 + r;
                    const int n = bx * 128 + wc * 64 + ni * 16 + l15;
                    Ofp[(size_t)m * DM + n] = acc[mi][ni][r];
                }
    } else if (wt == 2) {
#pragma unroll
        for (int mi = 0; mi < 4; ++mi)
#pragma unroll
            for (int ni = 0; ni < 4; ++ni) {
                ushort4 hv;
                unsigned short* hp_ = (unsigned short*)&hv;
#pragma unroll
                for (int r = 0; r < 4; ++r)
                    hp_[r] = (unsigned short)(cvtpk(acc[mi][ni][r], acc[mi][ni][r]) & 0xffffu);
                const int vrow = bx * 128 + wc * 64 + ni * 16 + l15;
                const size_t off = (size_t)vrow * SEQ + m0 + wr * 64 + mi * 16 + lg * 4;
                *reinterpret_cast<ushort4*>(&OVh[off]) = hv;
            }
    } else {
        unsigned short* Oh = (wt == 0) ? OQh : OKh;
        unsigned short* Ol = (wt == 0) ? OQl : OKl;
        const int head = bx * 2 + wc;
        const float qsc = 0.1803368801f;   // 0.125 * log2(e)
#pragma unroll
        for (int mi = 0; mi < 4; ++mi)
#pragma unroll
            for (int r = 0; r < 4; ++r) {
                const int m   = m0 + wr * 64 + mi * 16 + lg * 4 + r;
                const int pos = positions[m];
#pragma unroll
                for (int ni = 0; ni < 4; ++ni) {
                    float val = acc[mi][ni][r];
                    const int d = ni * 16 + l15;
                    const float other = __shfl_xor(val, 1);
                    const float cc = cosT[pos * 32 + ni * 8 + (l15 >> 1)];
                    const float ss = sinT[pos * 32 + ni * 8 + (l15 >> 1)];
                    val = (d & 1) ? fmaf(other, ss, val * cc)
                                  : fmaf(other, -ss, val * cc);
                    if (wt == 0) val *= qsc;
                    unsigned short hh, ll;
                    split1(val, hh, ll);
                    const size_t off = ((size_t)head * SEQ + m) * DK + d;
                    Oh[off] = hh; Ol[off] = ll;
                }
            }
    }
}

// ---------------------------------------------------------------------------
// MFMA flash attention with IN-BLOCK KEY-SPLIT for 3 waves/SIMD.
// 384-thread blocks = 3 key-groups x 2 waves. QBLK=64. Grid 512 = 2/CU.
// FIXED vs R11: staging now assembles the k-PERMUTED granule in registers
// (granule m = {cols 4m..+4, cols 16+4m..+4} within the 32-col half) before
// a single b128 write — matching the fragment-read layout validated in R8.
// R11 wrote contiguous granules, breaking A/B k-correspondence (absmax 2.2).
// ---------------------------------------------------------------------------
__global__ __launch_bounds__(384, 3)
void attn_mfma(const unsigned short* __restrict__ Qhi, const unsigned short* __restrict__ Qlo,
               const unsigned short* __restrict__ Khi, const unsigned short* __restrict__ Klo,
               const unsigned short* __restrict__ Vhi,
               unsigned short* __restrict__ Yh, unsigned short* __restrict__ Yl)
{
    __shared__ unsigned short KsH[3][64][64], KsL[3][64][64], Vs[3][64][64];
    __shared__ float2 mlLds[3][64];

    const int t    = threadIdx.x;
    const int lane = t & 63;
    const int wave = t >> 6;            // 0..5
    const int g    = wave >> 1;         // key-group 0..2
    const int w_in = wave & 1;          // wave within group
    const int bid  = blockIdx.x;
    const int h    = 2 * (bid & 7) + ((bid >> 3) & 1);
    const int p    = bid >> 4;          // pair index 0..31

    const int l15 = lane & 15, lg = lane >> 4, dg = lg * 4;
    const int gt   = t & 127;           // thread within group
    const int srow = gt >> 1;           // staging row 0..63
    const int ch   = gt & 1;            // col-half (32 cols)

    // swizzled granule base offsets (ushort units): granule G -> G^(row&7)
    int woff[4];
#pragma unroll
    for (int m = 0; m < 4; ++m)
        woff[m] = srow * 64 + (((ch * 4 + m) ^ (srow & 7)) << 3);

    unsigned short* ksh = &KsH[g][0][0];
    unsigned short* ksl = &KsL[g][0][0];
    unsigned short* vs  = &Vs[g][0][0];

    u16x8 pf[12];
    auto PREFETCH = [&](int kt) {
        const size_t gK = ((size_t)h * SEQ + (size_t)kt * 64 + srow) * DK + ch * 32;
        const size_t gV = ((size_t)h * DK + srow) * SEQ + (size_t)kt * 64 + ch * 32;
#pragma unroll
        for (int m = 0; m < 4; ++m) {
            pf[m]     = *reinterpret_cast<const u16x8*>(&Khi[gK + m * 8]);
            pf[4 + m] = *reinterpret_cast<const u16x8*>(&Klo[gK + m * 8]);
            pf[8 + m] = *reinterpret_cast<const u16x8*>(&Vhi[gV + m * 8]);
        }
    };
    // k-permuted granule assembly: granule m = {pf[m>>1].q[m&1], pf[2+(m>>1)].q[m&1]}
    auto STAGE = [&]() {
#pragma unroll
        for (int arr = 0; arr < 3; ++arr) {
            unsigned short* dst = (arr == 0) ? ksh : ((arr == 1) ? ksl : vs);
#pragma unroll
            for (int m = 0; m < 4; ++m) {
                FragU lo, hi, gr;
                lo.u = pf[arr * 4 + (m >> 1)];
                hi.u = pf[arr * 4 + 2 + (m >> 1)];
                gr.q[0] = lo.q[m & 1];
                gr.q[1] = hi.q[m & 1];
                *reinterpret_cast<u16x8*>(&dst[woff[m]]) = gr.u;
            }
        }
    };

    const int rb0 = w_in * 2;   // row-block of frag u = rb0 + u

#pragma unroll 1
    for (int phase = 0; phase < 2; ++phase) {
        const int qt     = phase ? (63 - p) : p;
        const int ntiles = qt + 1;
        const int nq     = ntiles / 3, rq = ntiles % 3;
        const int n_g    = nq + (g < rq ? 1 : 0);
        const int base   = g * nq + (g < rq ? g : rq);
        const int iters  = nq + (rq ? 1 : 0);

        // Q fragments: frag u = rows qt*64 + w_in*32 + u*16 + l15
        bf16x8 qh[2][2], ql[2][2];
#pragma unroll
        for (int u = 0; u < 2; ++u) {
            const size_t qrow = ((size_t)h * SEQ + (size_t)qt * 64 + w_in * 32 + u * 16 + l15) * DK;
#pragma unroll
            for (int c = 0; c < 2; ++c) {
                FragU uh, ul;
                uh.q[0] = *reinterpret_cast<const ushort4*>(&Qhi[qrow + c * 32 + dg]);
                uh.q[1] = *reinterpret_cast<const ushort4*>(&Qhi[qrow + c * 32 + 16 + dg]);
                ul.q[0] = *reinterpret_cast<const ushort4*>(&Qlo[qrow + c * 32 + dg]);
                ul.q[1] = *reinterpret_cast<const ushort4*>(&Qlo[qrow + c * 32 + 16 + dg]);
                qh[u][c] = uh.b; ql[u][c] = ul.b;
            }
        }

        f32x4 yacc[2][4];
#pragma unroll
        for (int u = 0; u < 2; ++u)
#pragma unroll
            for (int dt = 0; dt < 4; ++dt) yacc[u][dt] = (f32x4){0.f, 0.f, 0.f, 0.f};
        float m_run[2] = {-1e30f, -1e30f}, l_run[2] = {0.f, 0.f};

        if (n_g > 0) PREFETCH(base);

        for (int it = 0; it < iters; ++it) {
            __syncthreads();                 // prev reads of this buffer done
            if (it < n_g) STAGE();
            __syncthreads();                 // staging visible
            if (it + 1 < n_g) PREFETCH(base + it + 1);

            if (it < n_g) {
                const int kt   = base + it;
                const bool diag = (kt == qt);

                // ---- S^T = K * Q^T ----
                f32x4 st[2][4];
#pragma unroll
                for (int ktile = 0; ktile < 4; ++ktile) {
                    const int rowK = ktile * 16 + l15;
                    const int swk  = rowK & 7;
                    FragU kh0, kl0, kh1, kl1;
                    {
                        const int p0 = ((0 + lg) ^ swk) << 3;
                        const int p1 = ((4 + lg) ^ swk) << 3;
                        kh0.u = *reinterpret_cast<const u16x8*>(&ksh[rowK * 64 + p0]);
                        kl0.u = *reinterpret_cast<const u16x8*>(&ksl[rowK * 64 + p0]);
                        kh1.u = *reinterpret_cast<const u16x8*>(&ksh[rowK * 64 + p1]);
                        kl1.u = *reinterpret_cast<const u16x8*>(&ksl[rowK * 64 + p1]);
                    }
#pragma unroll
                    for (int u = 0; u < 2; ++u) {
                        if (diag && ktile > rb0 + u) {
                            st[u][ktile] = (f32x4){-1e30f, -1e30f, -1e30f, -1e30f};
                            continue;
                        }
                        f32x4 s0 = (f32x4){0.f, 0.f, 0.f, 0.f};
                        s0 = __builtin_amdgcn_mfma_f32_16x16x32_bf16(kh0.b, qh[u][0], s0, 0, 0, 0);
                        s0 = __builtin_amdgcn_mfma_f32_16x16x32_bf16(kh0.b, ql[u][0], s0, 0, 0, 0);
                        s0 = __builtin_amdgcn_mfma_f32_16x16x32_bf16(kl0.b, qh[u][0], s0, 0, 0, 0);
                        s0 = __builtin_amdgcn_mfma_f32_16x16x32_bf16(kh1.b, qh[u][1], s0, 0, 0, 0);
                        s0 = __builtin_amdgcn_mfma_f32_16x16x32_bf16(kh1.b, ql[u][1], s0, 0, 0, 0);
                        s0 = __builtin_amdgcn_mfma_f32_16x16x32_bf16(kl1.b, qh[u][1], s0, 0, 0, 0);
                        st[u][ktile] = s0;
                    }
                }

                if (diag) {
#pragma unroll
                    for (int u = 0; u < 2; ++u) {
                        const int ub = rb0 + u;
#pragma unroll
                        for (int r = 0; r < 4; ++r)
                            if (dg + r > l15) st[u][ub][r] = -1e30f;
                    }
                }

                // ---- online softmax (exp2 units, defer-max) ----
                bf16x8 pa[2][2];
#pragma unroll
                for (int u = 0; u < 2; ++u) {
                    float rowmax = st[u][0][0];
#pragma unroll
                    for (int ktile = 0; ktile < 4; ++ktile)
#pragma unroll
                        for (int r = 0; r < 4; ++r) rowmax = fmaxf(rowmax, st[u][ktile][r]);
                    rowmax = fmaxf(rowmax, __shfl_xor(rowmax, 16));
                    rowmax = fmaxf(rowmax, __shfl_xor(rowmax, 32));
                    if (!__all(rowmax <= m_run[u] + 11.5f)) {
                        const float mnew = fmaxf(m_run[u], rowmax);
                        const float factor = fexp2(m_run[u] - mnew);
                        l_run[u] *= factor;
#pragma unroll
                        for (int r = 0; r < 4; ++r) {
                            const float fr = __shfl(factor, (lg << 2) | r);
#pragma unroll
                            for (int dt = 0; dt < 4; ++dt) yacc[u][dt][r] *= fr;
                        }
                        m_run[u] = mnew;
                    }
                    float pp[4][4]; float psum = 0.f;
#pragma unroll
                    for (int ktile = 0; ktile < 4; ++ktile)
#pragma unroll
                        for (int r = 0; r < 4; ++r) {
                            pp[ktile][r] = fexp2(st[u][ktile][r] - m_run[u]);
                            psum += pp[ktile][r];
                        }
                    psum += __shfl_xor(psum, 16);
                    psum += __shfl_xor(psum, 32);
                    l_run[u] += psum;
#pragma unroll
                    for (int c = 0; c < 2; ++c) {
                        FragU P;
                        P.w[0] = cvtpk(pp[2 * c][0],     pp[2 * c][1]);
                        P.w[1] = cvtpk(pp[2 * c][2],     pp[2 * c][3]);
                        P.w[2] = cvtpk(pp[2 * c + 1][0], pp[2 * c + 1][1]);
                        P.w[3] = cvtpk(pp[2 * c + 1][2], pp[2 * c + 1][3]);
                        pa[u][c] = P.b;
                    }
                }

                // ---- y += P * V ----
#pragma unroll
                for (int dt = 0; dt < 4; ++dt) {
                    const int rowV = dt * 16 + l15;
                    const int swv  = rowV & 7;
#pragma unroll
                    for (int c = 0; c < 2; ++c) {
                        FragU vh;
                        vh.u = *reinterpret_cast<const u16x8*>(&vs[rowV * 64 + (((c * 4 + lg) ^ swv) << 3)]);
#pragma unroll
                        for (int u = 0; u < 2; ++u) {
                            if (diag && c == 1 && (rb0 + u) < 2) continue;
                            yacc[u][dt] = __builtin_amdgcn_mfma_f32_16x16x32_bf16(pa[u][c], vh.b, yacc[u][dt], 0, 0, 0);
                        }
                    }
                }
            } // active
        } // it

        // ---- 3-way in-block merge (exact online-softmax merge, fp32) ----
        __syncthreads();                     // all tile reads done
        if (lane < 16) {
            mlLds[g][w_in * 32 + lane]      = make_float2(m_run[0], l_run[0]);
            mlLds[g][w_in * 32 + 16 + lane] = make_float2(m_run[1], l_run[1]);
        }
        __syncthreads();

        float fg[2];
#pragma unroll
        for (int u = 0; u < 2; ++u) {
            const int row = w_in * 32 + u * 16 + l15;
            const float m0 = mlLds[0][row].x;
            const float m1 = mlLds[1][row].x;
            const float m2 = mlLds[2][row].x;
            const float mstar = fmaxf(fmaxf(m0, m1), m2);
            fg[u] = fexp2(m_run[u] - mstar);
        }

        float* fbuf = (float*)&KsH[0][0][0];   // [64][68] fp32, overlays KsH
#pragma unroll 1
        for (int gg = 0; gg < 3; ++gg) {
            if (g == gg) {
#pragma unroll
                for (int u = 0; u < 2; ++u)
#pragma unroll
                    for (int r = 0; r < 4; ++r) {
                        const float fr = __shfl(fg[u], (lg << 2) | r);
                        const int row = w_in * 32 + u * 16 + lg * 4 + r;
#pragma unroll
                        for (int dt = 0; dt < 4; ++dt) {
                            const int col = dt * 16 + l15;
                            if (gg == 0) fbuf[row * 68 + col]  = yacc[u][dt][r] * fr;
                            else         fbuf[row * 68 + col] += yacc[u][dt][r] * fr;
                        }
                    }
            }
            __syncthreads();
        }

        // final normalized write: 512 units = 64 rows x 8 col-groups
        for (int idx = t; idx < 512; idx += 384) {
            const int row = idx >> 3, cg = idx & 7;
            const float2 a0 = mlLds[0][row];
            const float2 a1 = mlLds[1][row];
            const float2 a2 = mlLds[2][row];
            const float mstar = fmaxf(fmaxf(a0.x, a1.x), a2.x);
            const float denom = fexp2(a0.x - mstar) * a0.y
                              + fexp2(a1.x - mstar) * a1.y
                              + fexp2(a2.x - mstar) * a2.y;
            const float inv = 1.0f / denom;
            ushort4 oh[2], ol[2];
#pragma unroll
            for (int half = 0; half < 2; ++half) {
                unsigned short* hp_ = (unsigned short*)&oh[half];
                unsigned short* lp_ = (unsigned short*)&ol[half];
#pragma unroll
                for (int j = 0; j < 4; ++j) {
                    const float o = fbuf[row * 68 + cg * 8 + half * 4 + j] * inv;
                    split1(o, hp_[j], lp_[j]);
                }
            }
            const size_t off = ((size_t)qt * 64 + row) * DM + h * DK + cg * 8;
            *reinterpret_cast<ushort4*>(&Yh[off])     = oh[0];
            *reinterpret_cast<ushort4*>(&Yh[off + 4]) = oh[1];
            *reinterpret_cast<ushort4*>(&Yl[off])     = ol[0];
            *reinterpret_cast<ushort4*>(&Yl[off + 4]) = ol[1];
        }
        // next phase's first __syncthreads separates fbuf reads from staging
    } // phases
}

// ---------------------------------------------------------------------------
extern "C" void kernel_launch(void* const* d_in, const int* in_sizes, int n_in,
                              void* d_out, int out_size, void* d_ws, size_t ws_size,
                              hipStream_t stream)
{
    const float* x    = (const float*)d_in[0];
    const float* Wq   = (const float*)d_in[1];
    const float* Wk   = (const float*)d_in[2];
    const float* Wv   = (const float*)d_in[3];
    const float* Wo   = (const float*)d_in[4];
    const float* cosT = (const float*)d_in[5];
    const float* sinT = (const float*)d_in[6];
    const int*   pos  = (const int*)d_in[7];
    float* out = (float*)d_out;

    // Workspace (56 MB): [xh|xl] (16, reused as yh|yl) + q/k/v splits (40)
    const size_t E = (size_t)SEQ * DM;
    unsigned short* xh = (unsigned short*)d_ws;   // later: yh
    unsigned short* xl = xh + E;                  // later: yl
    unsigned short* qh = xl + E;
    unsigned short* ql = qh + E;
    unsigned short* kh = ql + E;
    unsigned short* kl = kh + E;
    unsigned short* vh = kl + E;
    unsigned short* yh = xh;
    unsigned short* yl = xl;

    split_f32<<<dim3(1024), dim3(256), 0, stream>>>(x, xh, xl, (int)(E / 4));
    gemm_mfma<4><<<dim3(768), dim3(256), 0, stream>>>(
        xh, xl, Wq, Wk, Wv, qh, ql, kh, kl, vh, nullptr, cosT, sinT, pos);
    attn_mfma<<<dim3(512), dim3(384), 0, stream>>>(
        qh, ql, kh, kl, vh, yh, yl);
    gemm_mfma<0><<<dim3(256), dim3(256), 0, stream>>>(
        yh, yl, Wo, nullptr, nullptr,
        nullptr, nullptr, nullptr, nullptr, nullptr, out, cosT, sinT, pos);
}

// Round 13
// 262.545 us; speedup vs baseline: 2.2257x; 2.2257x over previous
//
#include <hip/hip_runtime.h>
#include <math.h>

#define SEQ 4096
#define DM  1024
#define NH  16
#define DK  64

typedef __attribute__((ext_vector_type(4))) float f32x4;
typedef __attribute__((ext_vector_type(8))) short bf16x8;
typedef __attribute__((ext_vector_type(8))) unsigned short u16x8;

union FragU { u16x8 u; bf16x8 b; ushort4 q[2]; unsigned w[4]; };

__device__ __forceinline__ unsigned cvtpk(float a, float b) {
    unsigned r; asm("v_cvt_pk_bf16_f32 %0, %1, %2" : "=v"(r) : "v"(a), "v"(b)); return r;
}
__device__ __forceinline__ float fexp2(float x) {
    float r; asm("v_exp_f32 %0, %1" : "=v"(r) : "v"(x)); return r;
}
__device__ __forceinline__ float bf_f(unsigned short s) {
    return __uint_as_float(((unsigned)s) << 16);
}
__device__ __forceinline__ void split4(float4 v, ushort4& hv, ushort4& lv) {
    union { ushort4 q; unsigned w[2]; } H, L;
    H.w[0] = cvtpk(v.x, v.y); H.w[1] = cvtpk(v.z, v.w);
    const float rx = v.x - __uint_as_float(H.w[0] << 16);
    const float ry = v.y - __uint_as_float(H.w[0] & 0xffff0000u);
    const float rz = v.z - __uint_as_float(H.w[1] << 16);
    const float rw = v.w - __uint_as_float(H.w[1] & 0xffff0000u);
    L.w[0] = cvtpk(rx, ry); L.w[1] = cvtpk(rz, rw);
    hv = H.q; lv = L.q;
}
__device__ __forceinline__ void split1(float f, unsigned short& h, unsigned short& l) {
    const unsigned hw = cvtpk(f, f) & 0xffffu;
    h = (unsigned short)hw;
    const float r = f - __uint_as_float(hw << 16);
    l = (unsigned short)(__float_as_uint(r) >> 16);
}

// ---------------------------------------------------------------------------
// Pre-split fp32 -> bf16 hi/lo (RNE).
// ---------------------------------------------------------------------------
__global__ __launch_bounds__(256)
void split_f32(const float* __restrict__ src, unsigned short* __restrict__ hi,
               unsigned short* __restrict__ lo, int n4)
{
    const int stride = gridDim.x * 256;
    for (int i = blockIdx.x * 256 + threadIdx.x; i < n4; i += stride) {
        const float4 v = reinterpret_cast<const float4*>(src)[i];
        ushort4 hv, lv;
        split4(v, hv, lv);
        reinterpret_cast<ushort4*>(hi)[i] = hv;
        reinterpret_cast<ushort4*>(lo)[i] = lv;
    }
}

// ---------------------------------------------------------------------------
// MFMA GEMM, 3-term bf16 hi/lo emulation. C = A * W^T.  (unchanged, validated)
// A pre-split bf16 hi/lo. W fp32, split in-loop.
// MODE 4: fused QKV (Q/K RoPE+store, V hi-only transposed). MODE 0: Wo->fp32.
// ---------------------------------------------------------------------------
template<int MODE>
__global__ __launch_bounds__(256, 2)
void gemm_mfma(const unsigned short* __restrict__ Ahi, const unsigned short* __restrict__ Alo,
               const float* __restrict__ W0, const float* __restrict__ W1,
               const float* __restrict__ W2,
               unsigned short* __restrict__ OQh, unsigned short* __restrict__ OQl,
               unsigned short* __restrict__ OKh, unsigned short* __restrict__ OKl,
               unsigned short* __restrict__ OVh,
               float* __restrict__ Ofp,
               const float* __restrict__ cosT, const float* __restrict__ sinT,
               const int* __restrict__ positions)
{
    constexpr int NT = (MODE == 4) ? 24 : 8;   // n-tiles of 128
    __shared__ unsigned short As[128][76];
    __shared__ unsigned short Bs[128][76];

    const int t   = threadIdx.x;
    const int bid = blockIdx.x;
    const int qpx = (32 * NT) >> 3;
    const int swz = (bid & 7) * qpx + (bid >> 3);
    const int by  = swz / NT;
    const int bxf = swz % NT;
    const int wt  = (MODE == 4) ? (bxf >> 3) : 0;
    const int bx  = (MODE == 4) ? (bxf & 7) : bxf;
    const int m0  = by * 128;
    const float* W = (MODE == 4) ? (wt == 0 ? W0 : (wt == 1 ? W1 : W2)) : W0;

    const int lane = t & 63, w = t >> 6;
    const int wr = w >> 1, wc = w & 1;
    const int l15 = lane & 15, lg = lane >> 4;

    const int ar = t >> 1, ah = t & 1;
    const unsigned short* Aph = &Ahi[(size_t)(m0 + ar) * DM + ah * 16];
    const unsigned short* Apl = &Alo[(size_t)(m0 + ar) * DM + ah * 16];
    const float* Wp = &W[(size_t)(bx * 128 + ar) * DM + ah * 16];

    f32x4 acc[4][4];
#pragma unroll
    for (int mi = 0; mi < 4; ++mi)
#pragma unroll
        for (int ni = 0; ni < 4; ++ni) acc[mi][ni] = (f32x4){0.f, 0.f, 0.f, 0.f};

    float4 pb[4];
    u16x8 pah[2], pal[2];
    pah[0] = *reinterpret_cast<const u16x8*>(Aph);
    pah[1] = *reinterpret_cast<const u16x8*>(Aph + 8);
    pal[0] = *reinterpret_cast<const u16x8*>(Apl);
    pal[1] = *reinterpret_cast<const u16x8*>(Apl + 8);
#pragma unroll
    for (int g = 0; g < 4; ++g) pb[g] = *reinterpret_cast<const float4*>(Wp + g * 4);

    for (int kt = 0; kt < 32; ++kt) {
        {
            FragU h0, h1, l0, l1;
            h0.u = pah[0]; h1.u = pah[1]; l0.u = pal[0]; l1.u = pal[1];
            *reinterpret_cast<ushort4*>(&As[ar][0  + 4 * ah]) = h0.q[0];
            *reinterpret_cast<ushort4*>(&As[ar][8  + 4 * ah]) = h0.q[1];
            *reinterpret_cast<ushort4*>(&As[ar][16 + 4 * ah]) = h1.q[0];
            *reinterpret_cast<ushort4*>(&As[ar][24 + 4 * ah]) = h1.q[1];
            *reinterpret_cast<ushort4*>(&As[ar][32 + 4 * ah]) = l0.q[0];
            *reinterpret_cast<ushort4*>(&As[ar][40 + 4 * ah]) = l0.q[1];
            *reinterpret_cast<ushort4*>(&As[ar][48 + 4 * ah]) = l1.q[0];
            *reinterpret_cast<ushort4*>(&As[ar][56 + 4 * ah]) = l1.q[1];
        }
#pragma unroll
        for (int g = 0; g < 4; ++g) {
            ushort4 hv, lv;
            split4(pb[g], hv, lv);
            *reinterpret_cast<ushort4*>(&Bs[ar][8 * g + 4 * ah])      = hv;
            *reinterpret_cast<ushort4*>(&Bs[ar][32 + 8 * g + 4 * ah]) = lv;
        }
        __syncthreads();

        if (kt < 31) {
            const int ko = (kt + 1) * 32;
            pah[0] = *reinterpret_cast<const u16x8*>(Aph + ko);
            pah[1] = *reinterpret_cast<const u16x8*>(Aph + ko + 8);
            pal[0] = *reinterpret_cast<const u16x8*>(Apl + ko);
            pal[1] = *reinterpret_cast<const u16x8*>(Apl + ko + 8);
#pragma unroll
            for (int g = 0; g < 4; ++g)
                pb[g] = *reinterpret_cast<const float4*>(Wp + ko + g * 4);
        }

        FragU b_h[4], b_l[4];
#pragma unroll
        for (int ni = 0; ni < 4; ++ni) {
            const int row = wc * 64 + ni * 16 + l15;
            b_h[ni].u = *reinterpret_cast<const u16x8*>(&Bs[row][8 * lg]);
            b_l[ni].u = *reinterpret_cast<const u16x8*>(&Bs[row][32 + 8 * lg]);
        }
#pragma unroll
        for (int mi = 0; mi < 4; ++mi) {
            FragU a_h, a_l;
            const int row = wr * 64 + mi * 16 + l15;
            a_h.u = *reinterpret_cast<const u16x8*>(&As[row][8 * lg]);
            a_l.u = *reinterpret_cast<const u16x8*>(&As[row][32 + 8 * lg]);
#pragma unroll
            for (int ni = 0; ni < 4; ++ni) {
                f32x4 c = acc[mi][ni];
                c = __builtin_amdgcn_mfma_f32_16x16x32_bf16(a_h.b, b_h[ni].b, c, 0, 0, 0);
                c = __builtin_amdgcn_mfma_f32_16x16x32_bf16(a_h.b, b_l[ni].b, c, 0, 0, 0);
                c = __builtin_amdgcn_mfma_f32_16x16x32_bf16(a_l.b, b_h[ni].b, c, 0, 0, 0);
                acc[mi][ni] = c;
            }
        }
        __syncthreads();
    }

    if constexpr (MODE == 0) {
#pragma unroll
        for (int mi = 0; mi < 4; ++mi)
#pragma unroll
            for (int ni = 0; ni < 4; ++ni)
#pragma unroll
                for (int r = 0; r < 4; ++r) {
                    const int m = m0 + wr * 64 + mi * 16 + lg * 4 + r;
                    const int n = bx * 128 + wc * 64 + ni * 16 + l15;
                    Ofp[(size_t)m * DM + n] = acc[mi][ni][r];
                }
    } else if (wt == 2) {
#pragma unroll
        for (int mi = 0; mi < 4; ++mi)
#pragma unroll
            for (int ni = 0; ni < 4; ++ni) {
                ushort4 hv;
                unsigned short* hp_ = (unsigned short*)&hv;
#pragma unroll
                for (int r = 0; r < 4; ++r)
                    hp_[r] = (unsigned short)(cvtpk(acc[mi][ni][r], acc[mi][ni][r]) & 0xffffu);
                const int vrow = bx * 128 + wc * 64 + ni * 16 + l15;
                const size_t off = (size_t)vrow * SEQ + m0 + wr * 64 + mi * 16 + lg * 4;
                *reinterpret_cast<ushort4*>(&OVh[off]) = hv;
            }
    } else {
        unsigned short* Oh = (wt == 0) ? OQh : OKh;
        unsigned short* Ol = (wt == 0) ? OQl : OKl;
        const int head = bx * 2 + wc;
        const float qsc = 0.1803368801f;   // 0.125 * log2(e)
#pragma unroll
        for (int mi = 0; mi < 4; ++mi)
#pragma unroll
            for (int r = 0; r < 4; ++r) {
                const int m   = m0 + wr * 64 + mi * 16 + lg * 4 + r;
                const int pos = positions[m];
#pragma unroll
                for (int ni = 0; ni < 4; ++ni) {
                    float val = acc[mi][ni][r];
                    const int d = ni * 16 + l15;
                    const float other = __shfl_xor(val, 1);
                    const float cc = cosT[pos * 32 + ni * 8 + (l15 >> 1)];
                    const float ss = sinT[pos * 32 + ni * 8 + (l15 >> 1)];
                    val = (d & 1) ? fmaf(other, ss, val * cc)
                                  : fmaf(other, -ss, val * cc);
                    if (wt == 0) val *= qsc;
                    unsigned short hh, ll;
                    split1(val, hh, ll);
                    const size_t off = ((size_t)head * SEQ + m) * DK + d;
                    Oh[off] = hh; Ol[off] = ll;
                }
            }
    }
}

// ---------------------------------------------------------------------------
// MFMA flash attention, uniform split blocks (R9 structure, validated) with
// 2-TERM QK: S = K_hi*(Q_hi + Q_lo)  (K-lo term dropped; dS ~ 2^-9 rel).
// Deletes KsL entirely: -33% QK MFMA, -33% LDS reads, -25% K traffic.
// QBLK=128, 4 waves x 32 rows, double-buffered LDS (32 KB), 2 blocks/CU.
// ---------------------------------------------------------------------------
__global__ __launch_bounds__(256, 2)
void attn_mfma(const unsigned short* __restrict__ Qhi, const unsigned short* __restrict__ Qlo,
               const unsigned short* __restrict__ Khi,
               const unsigned short* __restrict__ Vhi,
               unsigned short* __restrict__ Yh, unsigned short* __restrict__ Yl,
               unsigned short* __restrict__ Pb,
               float2* __restrict__ mlA, float2* __restrict__ mlB)
{
    __shared__ unsigned short KsH[2][64][64], Vs[2][64][64];

    const int t = threadIdx.x, lane = t & 63, w = t >> 6;
    const int bid  = blockIdx.x;
    const int xcd  = bid & 7;
    const int s    = bid >> 3;
    const int hl   = s & 1;
    const int slot = s >> 1;
    const int p    = slot & 15;
    const int half = slot >> 4;          // 0 = block A, 1 = block B
    const int h    = 2 * xcd + hl;

    const int l15 = lane & 15, lg = lane >> 4, dg = lg * 4;
    const int srow = t >> 2, q16 = t & 3;
    const int wh = w & 1;

    int wcol[4];
#pragma unroll
    for (int m = 0; m < 4; ++m) {
        const int g = (q16 >> 1) * 4 + m;
        wcol[m] = (((g ^ (srow & 7)) << 3) + ((q16 & 1) << 2));
    }

    u16x8 pf[4];
    auto PREFETCH = [&](int ktn) {
        const size_t gK = ((size_t)h * SEQ + (size_t)ktn * 64 + srow) * DK + q16 * 16;
        const size_t gV = ((size_t)h * DK + srow) * SEQ + (size_t)ktn * 64 + q16 * 16;
        pf[0] = *reinterpret_cast<const u16x8*>(&Khi[gK]);
        pf[1] = *reinterpret_cast<const u16x8*>(&Khi[gK + 8]);
        pf[2] = *reinterpret_cast<const u16x8*>(&Vhi[gV]);
        pf[3] = *reinterpret_cast<const u16x8*>(&Vhi[gV + 8]);
    };
    auto STAGE = [&](int b) {
        FragU f;
        f.u = pf[0];
        *reinterpret_cast<ushort4*>(&KsH[b][srow][wcol[0]]) = f.q[0];
        *reinterpret_cast<ushort4*>(&KsH[b][srow][wcol[1]]) = f.q[1];
        f.u = pf[1];
        *reinterpret_cast<ushort4*>(&KsH[b][srow][wcol[2]]) = f.q[0];
        *reinterpret_cast<ushort4*>(&KsH[b][srow][wcol[3]]) = f.q[1];
        f.u = pf[2];
        *reinterpret_cast<ushort4*>(&Vs[b][srow][wcol[0]]) = f.q[0];
        *reinterpret_cast<ushort4*>(&Vs[b][srow][wcol[1]]) = f.q[1];
        f.u = pf[3];
        *reinterpret_cast<ushort4*>(&Vs[b][srow][wcol[2]]) = f.q[0];
        *reinterpret_cast<ushort4*>(&Vs[b][srow][wcol[3]]) = f.q[1];
    };

    const int nph = (half == 0) ? 2 : 1;
#pragma unroll 1
    for (int ph = 0; ph < nph; ++ph) {
        const int qt    = (half == 0 && ph == 0) ? p : (31 - p);
        const int kt0   = (half == 1) ? (31 - 2 * p) : 0;
        const int kt1   = (half == 0) ? ((ph == 0) ? (2 * p + 2) : (31 - 2 * p))
                                      : (64 - 2 * p);
        const int emode = (half == 0) ? ph : 2;   // 0 final, 1 partialA, 2 partialB
        const int diagkt = 2 * qt + (w >> 1);

        bf16x8 qh[2][2], ql[2][2];
#pragma unroll
        for (int u = 0; u < 2; ++u) {
            const size_t qrow = ((size_t)h * SEQ + (size_t)qt * 128 + w * 32 + u * 16 + l15) * DK;
#pragma unroll
            for (int c = 0; c < 2; ++c) {
                FragU uh, ul;
                uh.q[0] = *reinterpret_cast<const ushort4*>(&Qhi[qrow + c * 32 + dg]);
                uh.q[1] = *reinterpret_cast<const ushort4*>(&Qhi[qrow + c * 32 + 16 + dg]);
                ul.q[0] = *reinterpret_cast<const ushort4*>(&Qlo[qrow + c * 32 + dg]);
                ul.q[1] = *reinterpret_cast<const ushort4*>(&Qlo[qrow + c * 32 + 16 + dg]);
                qh[u][c] = uh.b; ql[u][c] = ul.b;
            }
        }

        f32x4 yacc[2][4];
#pragma unroll
        for (int u = 0; u < 2; ++u)
#pragma unroll
            for (int dt = 0; dt < 4; ++dt) yacc[u][dt] = (f32x4){0.f, 0.f, 0.f, 0.f};
        float m_run[2] = {-1e30f, -1e30f}, l_run[2] = {0.f, 0.f};

        // prologue: stage tile kt0 into buf 0, start loading kt0+1
        PREFETCH(kt0);
        __syncthreads();            // prior phase's buffer reads all done
        STAGE(0);
        if (kt0 + 1 < kt1) PREFETCH(kt0 + 1);

        for (int kt = kt0; kt < kt1; ++kt) {
            const int b = (kt - kt0) & 1;
            __syncthreads();        // buf[b] writes visible; buf[b^1] free
            if (kt + 1 < kt1) {
                STAGE(b ^ 1);       // overlaps with compute below (independent)
                if (kt + 2 < kt1) PREFETCH(kt + 2);
            }

            if (kt <= diagkt) {
                const bool diag = (kt == diagkt);

                // ---- S^T = K_hi * (Q_hi + Q_lo)^T  (2-term) ----
                f32x4 st[2][4];
#pragma unroll
                for (int ktile = 0; ktile < 4; ++ktile) {
                    const int rowK = ktile * 16 + l15;
                    const int swk  = rowK & 7;
                    FragU kh0, kh1;
                    {
                        const int p0 = ((0 + lg) ^ swk) << 3;
                        const int p1 = ((4 + lg) ^ swk) << 3;
                        kh0.u = *reinterpret_cast<const u16x8*>(&KsH[b][rowK][p0]);
                        kh1.u = *reinterpret_cast<const u16x8*>(&KsH[b][rowK][p1]);
                    }
#pragma unroll
                    for (int u = 0; u < 2; ++u) {
                        if (diag && ktile > wh * 2 + u) {
                            st[u][ktile] = (f32x4){-1e30f, -1e30f, -1e30f, -1e30f};
                            continue;
                        }
                        f32x4 s0 = (f32x4){0.f, 0.f, 0.f, 0.f};
                        s0 = __builtin_amdgcn_mfma_f32_16x16x32_bf16(kh0.b, qh[u][0], s0, 0, 0, 0);
                        s0 = __builtin_amdgcn_mfma_f32_16x16x32_bf16(kh0.b, ql[u][0], s0, 0, 0, 0);
                        s0 = __builtin_amdgcn_mfma_f32_16x16x32_bf16(kh1.b, qh[u][1], s0, 0, 0, 0);
                        s0 = __builtin_amdgcn_mfma_f32_16x16x32_bf16(kh1.b, ql[u][1], s0, 0, 0, 0);
                        st[u][ktile] = s0;
                    }
                }

                if (diag) {
#pragma unroll
                    for (int u = 0; u < 2; ++u) {
                        const int ub = wh * 2 + u;
#pragma unroll
                        for (int r = 0; r < 4; ++r)
                            if (dg + r > l15) st[u][ub][r] = -1e30f;
                    }
                }

                // ---- online softmax (exp2 units, defer-max) ----
                bf16x8 pa[2][2];
#pragma unroll
                for (int u = 0; u < 2; ++u) {
                    float rowmax = st[u][0][0];
#pragma unroll
                    for (int ktile = 0; ktile < 4; ++ktile)
#pragma unroll
                        for (int r = 0; r < 4; ++r) rowmax = fmaxf(rowmax, st[u][ktile][r]);
                    rowmax = fmaxf(rowmax, __shfl_xor(rowmax, 16));
                    rowmax = fmaxf(rowmax, __shfl_xor(rowmax, 32));
                    if (!__all(rowmax <= m_run[u] + 11.5f)) {
                        const float mnew = fmaxf(m_run[u], rowmax);
                        const float factor = fexp2(m_run[u] - mnew);
                        l_run[u] *= factor;
#pragma unroll
                        for (int r = 0; r < 4; ++r) {
                            const float fr = __shfl(factor, (lg << 2) | r);
#pragma unroll
                            for (int dt = 0; dt < 4; ++dt) yacc[u][dt][r] *= fr;
                        }
                        m_run[u] = mnew;
                    }
                    float pp[4][4]; float psum = 0.f;
#pragma unroll
                    for (int ktile = 0; ktile < 4; ++ktile)
#pragma unroll
                        for (int r = 0; r < 4; ++r) {
                            pp[ktile][r] = fexp2(st[u][ktile][r] - m_run[u]);
                            psum += pp[ktile][r];
                        }
                    psum += __shfl_xor(psum, 16);
                    psum += __shfl_xor(psum, 32);
                    l_run[u] += psum;
#pragma unroll
                    for (int c = 0; c < 2; ++c) {
                        FragU P;
                        P.w[0] = cvtpk(pp[2 * c][0],     pp[2 * c][1]);
                        P.w[1] = cvtpk(pp[2 * c][2],     pp[2 * c][3]);
                        P.w[2] = cvtpk(pp[2 * c + 1][0], pp[2 * c + 1][1]);
                        P.w[3] = cvtpk(pp[2 * c + 1][2], pp[2 * c + 1][3]);
                        pa[u][c] = P.b;
                    }
                }

                // ---- y += P * V ----
#pragma unroll
                for (int dt = 0; dt < 4; ++dt) {
                    const int rowV = dt * 16 + l15;
                    const int swv  = rowV & 7;
#pragma unroll
                    for (int c = 0; c < 2; ++c) {
                        FragU vh;
                        vh.u = *reinterpret_cast<const u16x8*>(&Vs[b][rowV][((c * 4 + lg) ^ swv) << 3]);
#pragma unroll
                        for (int u = 0; u < 2; ++u) {
                            if (diag && c == 1 && (wh * 2 + u) < 2) continue;
                            yacc[u][dt] = __builtin_amdgcn_mfma_f32_16x16x32_bf16(pa[u][c], vh.b, yacc[u][dt], 0, 0, 0);
                        }
                    }
                }
            } // active
        } // kt

        // ---- epilogue ----
        if (emode == 0) {
#pragma unroll
            for (int u = 0; u < 2; ++u) {
                const float inv = 1.0f / l_run[u];
#pragma unroll
                for (int r = 0; r < 4; ++r) {
                    const float ir = __shfl(inv, (lg << 2) | r);
                    const size_t row = (size_t)qt * 128 + w * 32 + u * 16 + lg * 4 + r;
#pragma unroll
                    for (int dt = 0; dt < 4; ++dt) {
                        unsigned short hh, ll;
                        split1(yacc[u][dt][r] * ir, hh, ll);
                        const size_t off = row * DM + h * DK + dt * 16 + l15;
                        Yh[off] = hh; Yl[off] = ll;
                    }
                }
            }
        } else if (emode == 1) {
#pragma unroll
            for (int u = 0; u < 2; ++u) {
#pragma unroll
                for (int r = 0; r < 4; ++r) {
                    const size_t row = (size_t)qt * 128 + w * 32 + u * 16 + lg * 4 + r;
#pragma unroll
                    for (int dt = 0; dt < 4; ++dt) {
                        unsigned short hh, ll;
                        split1(yacc[u][dt][r], hh, ll);
                        const size_t off = row * DM + h * DK + dt * 16 + l15;
                        Yh[off] = hh; Yl[off] = ll;
                    }
                }
                if (lane < 16)
                    mlA[(h * 16 + p) * 128 + w * 32 + u * 16 + lane] =
                        make_float2(m_run[u], l_run[u]);
            }
        } else {
#pragma unroll
            for (int u = 0; u < 2; ++u) {
#pragma unroll
                for (int r = 0; r < 4; ++r) {
                    const int rloc = w * 32 + u * 16 + lg * 4 + r;
#pragma unroll
                    for (int dt = 0; dt < 4; ++dt) {
                        Pb[((size_t)(h * 16 + p) * 128 + rloc) * 64 + dt * 16 + l15] =
                            (unsigned short)(cvtpk(yacc[u][dt][r], yacc[u][dt][r]) & 0xffffu);
                    }
                }
                if (lane < 16)
                    mlB[(h * 16 + p) * 128 + w * 32 + u * 16 + lane] =
                        make_float2(m_run[u], l_run[u]);
            }
        }
    } // phases
}

// ---------------------------------------------------------------------------
// Merge the two partials of each heavy q-tile (exact online-softmax merge).
// ---------------------------------------------------------------------------
__global__ __launch_bounds__(256)
void merge_heavy(unsigned short* __restrict__ Yh, unsigned short* __restrict__ Yl,
                 const unsigned short* __restrict__ Pb,
                 const float2* __restrict__ mlA, const float2* __restrict__ mlB)
{
    const int hp = blockIdx.x;
    const int h = hp >> 4, p = hp & 15;
    const int t = threadIdx.x;
    const int row = t >> 1;
    const int d0 = (t & 1) * 32;
    const float2 a = mlA[hp * 128 + row];
    const float2 b = mlB[hp * 128 + row];
    const float m  = fmaxf(a.x, b.x);
    const float fA = fexp2(a.x - m), fB = fexp2(b.x - m);
    const float inv = 1.0f / (fA * a.y + fB * b.y);
    const size_t rg = ((size_t)(31 - p) * 128 + row) * DM + h * DK + d0;
    const size_t pg = ((size_t)hp * 128 + row) * 64 + d0;
#pragma unroll
    for (int dd = 0; dd < 32; dd += 8) {
        u16x8 vh = *reinterpret_cast<const u16x8*>(&Yh[rg + dd]);
        u16x8 vl = *reinterpret_cast<const u16x8*>(&Yl[rg + dd]);
        u16x8 vb = *reinterpret_cast<const u16x8*>(&Pb[pg + dd]);
        u16x8 oh, ol;
#pragma unroll
        for (int j = 0; j < 8; ++j) {
            const float ya = bf_f(vh[j]) + bf_f(vl[j]);
            const float yb = bf_f(vb[j]);
            const float o  = (fA * ya + fB * yb) * inv;
            unsigned short hh, ll;
            split1(o, hh, ll);
            oh[j] = hh; ol[j] = ll;
        }
        *reinterpret_cast<u16x8*>(&Yh[rg + dd]) = oh;
        *reinterpret_cast<u16x8*>(&Yl[rg + dd]) = ol;
    }
}

// ---------------------------------------------------------------------------
extern "C" void kernel_launch(void* const* d_in, const int* in_sizes, int n_in,
                              void* d_out, int out_size, void* d_ws, size_t ws_size,
                              hipStream_t stream)
{
    const float* x    = (const float*)d_in[0];
    const float* Wq   = (const float*)d_in[1];
    const float* Wk   = (const float*)d_in[2];
    const float* Wv   = (const float*)d_in[3];
    const float* Wo   = (const float*)d_in[4];
    const float* cosT = (const float*)d_in[5];
    const float* sinT = (const float*)d_in[6];
    const int*   pos  = (const int*)d_in[7];
    float* out = (float*)d_out;

    // Workspace (60.5 MB): [xh|xl] (16, reused as yh|yl) + q/k/v (40)
    // + Pb (4) + ml (0.5).  kl is written by the GEMM but unused by attn.
    const size_t E = (size_t)SEQ * DM;
    unsigned short* xh = (unsigned short*)d_ws;   // later: yh
    unsigned short* xl = xh + E;                  // later: yl
    unsigned short* qh = xl + E;
    unsigned short* ql = qh + E;
    unsigned short* kh = ql + E;
    unsigned short* kl = kh + E;
    unsigned short* vh = kl + E;
    unsigned short* Pb = vh + E;                  // 256*128*64 ushorts (4 MB)
    float2* mlA = (float2*)(Pb + (size_t)256 * 128 * 64);
    float2* mlB = mlA + (size_t)256 * 128;
    unsigned short* yh = xh;
    unsigned short* yl = xl;

    split_f32<<<dim3(1024), dim3(256), 0, stream>>>(x, xh, xl, (int)(E / 4));
    gemm_mfma<4><<<dim3(768), dim3(256), 0, stream>>>(
        xh, xl, Wq, Wk, Wv, qh, ql, kh, kl, vh, nullptr, cosT, sinT, pos);
    attn_mfma<<<dim3(512), dim3(256), 0, stream>>>(
        qh, ql, kh, vh, yh, yl, Pb, mlA, mlB);
    merge_heavy<<<dim3(256), dim3(256), 0, stream>>>(yh, yl, Pb, mlA, mlB);
    gemm_mfma<0><<<dim3(256), dim3(256), 0, stream>>>(
        yh, yl, Wo, nullptr, nullptr,
        nullptr, nullptr, nullptr, nullptr, nullptr, out, cosT, sinT, pos);
}